// Round 4
// baseline (870.292 us; speedup 1.0000x reference)
//
#include <hip/hip_runtime.h>
#include <cstdint>
#include <cstddef>

// ---------------------------------------------------------------------------
// TGNN fused pipeline v4.
//  - seg_kernel: one block per FULL segment (100 rows, M=112, 7 m-tiles),
//    512 threads (8 waves). Halves per-CU B-weight traffic vs half-segment
//    blocks and writes h_pair directly (no psum/combine).
//  - __launch_bounds__(512,2): 256-VGPR budget -> no accumulator spill
//    (R3's (256,3) spilled: WRITE_SIZE 8->238 MB).
//  - All B-fragments of each barrier-free stretch prefetched upfront
//    (register slack: per-wave accs only 84 regs).
//  - head1: f1 over 500 blocks; head2: f2+f3, wave-per-16-rows.
// ---------------------------------------------------------------------------

typedef __bf16 bf16;
typedef __attribute__((ext_vector_type(8))) __bf16 bf16x8;
typedef __attribute__((ext_vector_type(4))) __bf16 bf16x4;
typedef __attribute__((ext_vector_type(4))) float floatx4;

// packed-ws element offsets (bf16 elements)
#define WOFF_AW 0
#define WOFF_BW 8192
#define WOFF_P1 12288
#define WOFF_P2 208896
#define WOFF_P3 339968
#define WOFF_F1 602112
#define WOFF_F2 1126400
#define WOFF_HP 1142784          // h_pair [2000][1024] bf16
#define WOFF_H2 3190784          // h2 [2000][512] bf16

// LDS strides (bf16 elems), %8==0; (stride/2)%32 = 4 or 20 -> even bank spread
#define LSTR_H  392
#define LSTR_H2 136
#define LSTR_H3 264
#define LSTR_P  168

static __device__ __forceinline__ floatx4 mfma16(bf16x8 a, bf16x8 b, floatx4 c) {
  return __builtin_amdgcn_mfma_f32_16x16x32_bf16(a, b, c, 0, 0, 0);
}

// ---------------------------------------------------------------------------
// One-launch weight repack. fp32 row-major [K][N] -> bf16 fragment order:
// dst[((nc*KT + kt)*CW + nl)*32 + kk] = src[(kt*32+kk)*N + nc*CW + nl]
// ---------------------------------------------------------------------------
static __device__ __forceinline__ void pack_one(const float* __restrict__ src,
                                                bf16* __restrict__ dst, int i,
                                                int K, int N, int CW) {
  int kk = i & 31;
  int t = i >> 5;
  int nl = t % CW;
  int t2 = t / CW;
  int KT = K >> 5;
  int kt = t2 % KT;
  int nc = t2 / KT;
  dst[i] = (bf16)src[(kt * 32 + kk) * N + nc * CW + nl];
}

__global__ void pack_all(const float* __restrict__ aw, const float* __restrict__ bw,
                         const float* __restrict__ p1w, const float* __restrict__ p2w,
                         const float* __restrict__ p3w, const float* __restrict__ f1w,
                         const float* __restrict__ f2w, bf16* __restrict__ wpk) {
  int i = blockIdx.x * 256 + threadIdx.x;   // grid = WOFF_HP/256 exactly
  if (i < WOFF_BW)            pack_one(aw,  wpk + WOFF_AW, i - WOFF_AW,  64, 128, 128);
  else if (i < WOFF_P1)       pack_one(bw,  wpk + WOFF_BW, i - WOFF_BW,  32, 128, 128);
  else if (i < WOFF_P2)       pack_one(p1w, wpk + WOFF_P1, i - WOFF_P1, 384, 512, 128);
  else if (i < WOFF_P3)       pack_one(p2w, wpk + WOFF_P2, i - WOFF_P2, 512, 256, 128);
  else if (i < WOFF_F1)       pack_one(p3w, wpk + WOFF_P3, i - WOFF_P3, 256, 1024, 128);
  else if (i < WOFF_F2)       pack_one(f1w, wpk + WOFF_F1, i - WOFF_F1, 1024, 512, 128);
  else                        pack_one(f2w, wpk + WOFF_F2, i - WOFF_F2, 512, 32, 32);
}

// ---------------------------------------------------------------------------
// seg_kernel: 512 threads, 8 waves (wave w = n-tile owner), one full segment.
// LDS: hA h[100x392] | hB h2chunk[100x136] | pbuf pairs[100x168] = 139.2 KB.
// h3[100x264] overlays hA (safe: all hA reads complete before h3 writes).
// Pad rows 100..111: A-reads clamp row to 99 (dupes excluded from final sum).
// ---------------------------------------------------------------------------
__global__ __launch_bounds__(512, 2) void seg_kernel(
    const float* __restrict__ pairs, const int* __restrict__ idxp,
    const float* __restrict__ ab, const float* __restrict__ bb,
    const float* __restrict__ p1b, const float* __restrict__ p2b,
    const float* __restrict__ p3b, const bf16* __restrict__ wpk,
    bf16* __restrict__ hpair) {
  __shared__ __align__(16) bf16 smem[69600];
  bf16* const hA   = smem;           // h   [100 x 392]
  bf16* const hB   = smem + 39200;   // h2c [100 x 136]
  bf16* const pbuf = smem + 52800;   // prs [100 x 168]
  bf16* const h3   = smem;           // h3  [100 x 264] overlays hA

  const int tid = threadIdx.x;
  const int w = tid >> 6;            // 0..7
  const int lane = tid & 63;
  const int lm = lane & 15;
  const int lq = lane >> 4;
  const int seg = blockIdx.x;

  int rm[7];
#pragma unroll
  for (int mt = 0; mt < 7; ++mt) rm[mt] = min(mt * 16 + lm, 99);

  // ---- stage pairs [100,160] fp32 -> bf16 LDS ----
  {
    const float4* src = (const float4*)(pairs + (size_t)seg * 16000);
    for (int i = tid; i < 4000; i += 512) {
      int row = i / 40;
      int c4 = (i - row * 40) * 4;
      float4 v = src[i];
      bf16x4 o = {(bf16)v.x, (bf16)v.y, (bf16)v.z, (bf16)v.w};
      *(bf16x4*)(pbuf + row * LSTR_P + c4) = o;
    }
  }
  __syncthreads();

  const floatx4 fz = {0.f, 0.f, 0.f, 0.f};
  floatx4 acc7[7];
  floatx4 acc3[14];

  // ---------------- embed: a1 / a2 / be -> hA[100,384] -------------------
#pragma unroll
  for (int sub = 0; sub < 3; ++sub) {
    const int acol = sub * 64;
    const int nk = (sub == 2) ? 1 : 2;
    const bf16* wsrc = wpk + ((sub == 2) ? WOFF_BW : WOFF_AW);
    const float* bias = (sub == 2) ? bb : ab;
#pragma unroll
    for (int t = 0; t < 7; ++t) acc7[t] = fz;
    for (int kt = 0; kt < nk; ++kt) {
      bf16x8 b = *(const bf16x8*)(wsrc + ((size_t)(kt * 128 + w * 16 + lm)) * 32 + lq * 8);
#pragma unroll
      for (int mt = 0; mt < 7; ++mt) {
        bf16x8 a = *(const bf16x8*)(pbuf + rm[mt] * LSTR_P + acol + kt * 32 + lq * 8);
        acc7[mt] = mfma16(a, b, acc7[mt]);
      }
    }
    float bv = bias[w * 16 + lm];
#pragma unroll
    for (int mt = 0; mt < 7; ++mt)
#pragma unroll
      for (int r = 0; r < 4; ++r) {
        int row = mt * 16 + lq * 4 + r;
        float vv = acc7[mt][r] + bv;
        vv = vv > 0.f ? vv : 0.f;
        if (row < 100) hA[row * LSTR_H + sub * 128 + w * 16 + lm] = (bf16)vv;
      }
  }
  __syncthreads();

  // ------- p1 (4 N-chunks of 128), each fused into p2 K-accumulation -------
#pragma unroll
  for (int t = 0; t < 14; ++t) acc3[t] = fz;

  for (int nc = 0; nc < 4; ++nc) {
#pragma unroll
    for (int t = 0; t < 7; ++t) acc7[t] = fz;
    // prefetch ALL 12 B-frags for this chunk upfront (48 VGPRs)
    bf16x8 bq[12];
#pragma unroll
    for (int kt = 0; kt < 12; ++kt)
      bq[kt] = *(const bf16x8*)(wpk + WOFF_P1 +
                 ((size_t)((nc * 12 + kt) * 128 + w * 16 + lm)) * 32 + lq * 8);
#pragma unroll
    for (int kt = 0; kt < 12; ++kt)
#pragma unroll
      for (int mt = 0; mt < 7; ++mt) {
        bf16x8 a = *(const bf16x8*)(hA + rm[mt] * LSTR_H + kt * 32 + lq * 8);
        acc7[mt] = mfma16(a, bq[kt], acc7[mt]);
      }
    __syncthreads();                      // prior p2 reads of hB done (WAR)
    {
      float bv = p1b[nc * 128 + w * 16 + lm];
#pragma unroll
      for (int mt = 0; mt < 7; ++mt)
#pragma unroll
        for (int r = 0; r < 4; ++r) {
          int row = mt * 16 + lq * 4 + r;
          float vv = acc7[mt][r] + bv;
          vv = vv > 0.f ? vv : 0.f;
          if (row < 100) hB[row * LSTR_H2 + w * 16 + lm] = (bf16)vv;
        }
    }
    __syncthreads();                      // hB visible
    // p2 partial: wave owns n-tiles 2w, 2w+1; prefetch all 8 B-frags
    bf16x8 bp[8];
#pragma unroll
    for (int kt2 = 0; kt2 < 4; ++kt2)
#pragma unroll
      for (int j = 0; j < 2; ++j) {
        int t = 2 * w + j;
        bp[kt2 * 2 + j] = *(const bf16x8*)(wpk + WOFF_P2 +
            ((size_t)(((t >> 3) * 16 + nc * 4 + kt2) * 128 + (t & 7) * 16 + lm)) * 32 +
            lq * 8);
      }
#pragma unroll
    for (int kt2 = 0; kt2 < 4; ++kt2)
#pragma unroll
      for (int mt = 0; mt < 7; ++mt) {
        bf16x8 a = *(const bf16x8*)(hB + rm[mt] * LSTR_H2 + kt2 * 32 + lq * 8);
        acc3[mt * 2]     = mfma16(a, bp[kt2 * 2],     acc3[mt * 2]);
        acc3[mt * 2 + 1] = mfma16(a, bp[kt2 * 2 + 1], acc3[mt * 2 + 1]);
      }
  }

  // p2 epilogue: h3 = relu(acc3 + p2b) -> h3 (overlays hA). All waves passed
  // the nc=3 in-loop barriers -> hA reads complete; h3 disjoint from hB.
#pragma unroll
  for (int j = 0; j < 2; ++j) {
    int cl = (2 * w + j) * 16 + lm;
    float bv = p2b[cl];
#pragma unroll
    for (int mt = 0; mt < 7; ++mt)
#pragma unroll
      for (int r = 0; r < 4; ++r) {
        int row = mt * 16 + lq * 4 + r;
        float vv = acc3[mt * 2 + j][r] + bv;
        vv = vv > 0.f ? vv : 0.f;
        if (row < 100) h3[row * LSTR_H3 + cl] = (bf16)vv;
      }
  }
  __syncthreads();

  // ---------------- p3 (4 N-chunks of 256) + masked column sums ----------
  const float cnt = (float)idxp[seg];
  for (int c = 0; c < 4; ++c) {
#pragma unroll
    for (int t = 0; t < 14; ++t) acc3[t] = fz;
    // prefetch all 16 B-frags (64 VGPRs)
    bf16x8 bq[16];
#pragma unroll
    for (int kt = 0; kt < 8; ++kt)
#pragma unroll
      for (int j = 0; j < 2; ++j) {
        int t = 2 * w + j;
        bq[kt * 2 + j] = *(const bf16x8*)(wpk + WOFF_P3 +
            ((size_t)(((2 * c + (t >> 3)) * 8 + kt) * 128 + (t & 7) * 16 + lm)) * 32 +
            lq * 8);
      }
#pragma unroll
    for (int kt = 0; kt < 8; ++kt)
#pragma unroll
      for (int mt = 0; mt < 7; ++mt) {
        bf16x8 a = *(const bf16x8*)(h3 + rm[mt] * LSTR_H3 + kt * 32 + lq * 8);
        acc3[mt * 2]     = mfma16(a, bq[kt * 2],     acc3[mt * 2]);
        acc3[mt * 2 + 1] = mfma16(a, bq[kt * 2 + 1], acc3[mt * 2 + 1]);
      }
    // masked column sums: rows mt*16+lq*4+r valid iff <100
    // mt<6: all; mt==6: lq==0 only (rows 96..99); clamped dupes excluded.
#pragma unroll
    for (int j = 0; j < 2; ++j) {
      float cs = 0.f;
#pragma unroll
      for (int mt = 0; mt < 7; ++mt) {
        floatx4 cc = acc3[mt * 2 + j];
        float t4 = cc[0] + cc[1] + cc[2] + cc[3];
        if (mt == 6 && lq != 0) t4 = 0.f;
        cs += t4;
      }
      cs += __shfl_xor(cs, 16, 64);
      cs += __shfl_xor(cs, 32, 64);
      if (lq == 0) {
        int col = c * 256 + (2 * w + j) * 16 + lm;
        hpair[(size_t)seg * 1024 + col] = (bf16)(cs / cnt + p3b[col]);
      }
    }
  }
}

// ---------------------------------------------------------------------------
// head1: f1 = relu(h_pair @ f1w + f1b) -> h2 ws. 500 blocks: 125 row-groups
// x 4 col-chunks of 128. 4 waves/block, wave owns n-tiles 2w,2w+1.
// ---------------------------------------------------------------------------
__global__ __launch_bounds__(256, 2) void head1_kernel(
    const bf16* __restrict__ wpk, const bf16* __restrict__ hpair,
    const float* __restrict__ f1b, bf16* __restrict__ h2) {
  const int tid = threadIdx.x;
  const int w = tid >> 6;
  const int lane = tid & 63;
  const int lm = lane & 15;
  const int lq = lane >> 4;
  const int rg = blockIdx.x >> 2;
  const int cc = blockIdx.x & 3;
  const int r0 = rg * 16;
  const floatx4 fz = {0.f, 0.f, 0.f, 0.f};

  floatx4 a2[2];
  a2[0] = fz; a2[1] = fz;
#pragma unroll 8
  for (int kt = 0; kt < 32; ++kt) {
    bf16x8 a = *(const bf16x8*)(hpair + (size_t)(r0 + lm) * 1024 + kt * 32 + lq * 8);
#pragma unroll
    for (int j = 0; j < 2; ++j) {
      bf16x8 b = *(const bf16x8*)(wpk + WOFF_F1 +
                    ((size_t)((cc * 32 + kt) * 128 + (2 * w + j) * 16 + lm)) * 32 + lq * 8);
      a2[j] = mfma16(a, b, a2[j]);
    }
  }
#pragma unroll
  for (int j = 0; j < 2; ++j) {
    int col = cc * 128 + (2 * w + j) * 16 + lm;
    float bv = f1b[col];
#pragma unroll
    for (int r = 0; r < 4; ++r) {
      float v = a2[j][r] + bv;
      v = v > 0.f ? v : 0.f;
      h2[(size_t)(r0 + lq * 4 + r) * 512 + col] = (bf16)v;
    }
  }
}

// ---------------------------------------------------------------------------
// head2: f2 (relu) + f3. Wave-per-16-rows, 32 blocks x 4 waves (125 groups).
// ---------------------------------------------------------------------------
__global__ __launch_bounds__(256, 2) void head2_kernel(
    const bf16* __restrict__ wpk, const bf16* __restrict__ h2,
    const float* __restrict__ f2b, const float* __restrict__ f3w,
    const float* __restrict__ f3b, float* __restrict__ out) {
  __shared__ __align__(16) bf16 h3s[4][16 * 40];

  const int tid = threadIdx.x;
  const int w = tid >> 6;
  const int lane = tid & 63;
  const int lm = lane & 15;
  const int lq = lane >> 4;
  const int rg = blockIdx.x * 4 + w;
  if (rg >= 125) return;
  const int r0 = rg * 16;
  const floatx4 fz = {0.f, 0.f, 0.f, 0.f};

  floatx4 c2[2];
  c2[0] = fz; c2[1] = fz;
#pragma unroll
  for (int kt = 0; kt < 16; ++kt) {
    bf16x8 a = *(const bf16x8*)(h2 + (size_t)(r0 + lm) * 512 + kt * 32 + lq * 8);
#pragma unroll
    for (int j = 0; j < 2; ++j) {
      bf16x8 b = *(const bf16x8*)(wpk + WOFF_F2 +
                    ((size_t)(kt * 32 + j * 16 + lm)) * 32 + lq * 8);
      c2[j] = mfma16(a, b, c2[j]);
    }
  }
#pragma unroll
  for (int j = 0; j < 2; ++j) {
    int col = j * 16 + lm;
    float bv = f2b[col];
#pragma unroll
    for (int r = 0; r < 4; ++r) {
      float v = c2[j][r] + bv;
      v = v > 0.f ? v : 0.f;
      h3s[w][(lq * 4 + r) * 40 + col] = (bf16)v;
    }
  }
  float ps = 0.f;
#pragma unroll
  for (int jj = 0; jj < 8; ++jj)
    ps += (float)h3s[w][lm * 40 + lq * 8 + jj] * f3w[lq * 8 + jj];
  ps += __shfl_xor(ps, 16, 64);
  ps += __shfl_xor(ps, 32, 64);
  if (lq == 0) out[r0 + lm] = ps + f3b[0];
}

// ---------------------------------------------------------------------------
extern "C" void kernel_launch(void* const* d_in, const int* in_sizes, int n_in,
                              void* d_out, int out_size, void* d_ws,
                              size_t ws_size, hipStream_t stream) {
  (void)in_sizes; (void)n_in; (void)out_size; (void)ws_size;
  const float* pairs = (const float*)d_in[0];
  const int*   idxp  = (const int*)d_in[1];
  // d_in[2] = ref_feats (unused by the reference)
  const float* aw  = (const float*)d_in[3];
  const float* ab  = (const float*)d_in[4];
  const float* bw  = (const float*)d_in[5];
  const float* bb  = (const float*)d_in[6];
  const float* p1w = (const float*)d_in[7];
  const float* p1b = (const float*)d_in[8];
  const float* p2w = (const float*)d_in[9];
  const float* p2b = (const float*)d_in[10];
  const float* p3w = (const float*)d_in[11];
  const float* p3b = (const float*)d_in[12];
  const float* f1w = (const float*)d_in[13];
  const float* f1b = (const float*)d_in[14];
  const float* f2w = (const float*)d_in[15];
  const float* f2b = (const float*)d_in[16];
  const float* f3w = (const float*)d_in[17];
  const float* f3b = (const float*)d_in[18];

  bf16* wpk = (bf16*)d_ws;

  pack_all<<<WOFF_HP / 256, 256, 0, stream>>>(aw, bw, p1w, p2w, p3w, f1w, f2w,
                                              wpk);
  seg_kernel<<<2000, 512, 0, stream>>>(pairs, idxp, ab, bb, p1b, p2b, p3b, wpk,
                                       wpk + WOFF_HP);
  head1_kernel<<<500, 256, 0, stream>>>(wpk, wpk + WOFF_HP, f1b,
                                        wpk + WOFF_H2);
  head2_kernel<<<32, 256, 0, stream>>>(wpk, wpk + WOFF_H2, f2b, f3w, f3b,
                                       (float*)d_out);
}

// Round 5
// 637.333 us; speedup vs baseline: 1.3655x; 1.3655x over previous
//
#include <hip/hip_runtime.h>
#include <cstdint>
#include <cstddef>

// ---------------------------------------------------------------------------
// TGNN fused pipeline v5 (= v3 structure, fixed register budget).
//  - seg_kernel: one block per half-segment (50 rows). LDS 52.8 KB
//    (50-row tiles, clamped pad-row reads, no pairs staging buffer)
//    -> 3 blocks/CU by LDS.
//  - __launch_bounds__(256,2): 256-VGPR budget. R3's (256,3) made the
//    compiler target 84 VGPR -> accumulator spill (WRITE_SIZE 8->238 MB).
//    R2 proved this code shape fits in ~108 VGPR with (256,2).
//  - B-fragments straight from packed global weights (L1/L2-hot).
//  - pack_all: all 7 weight repacks in ONE launch.
//  - head_kernel: combine (segment mean + p3 bias) fused in front of f1/f2/f3.
// ---------------------------------------------------------------------------

typedef __bf16 bf16;
typedef __attribute__((ext_vector_type(8))) __bf16 bf16x8;
typedef __attribute__((ext_vector_type(4))) float floatx4;

// packed-ws element offsets (bf16 elements)
#define WOFF_AW 0
#define WOFF_BW 8192
#define WOFF_P1 12288
#define WOFF_P2 208896
#define WOFF_P3 339968
#define WOFF_F1 602112
#define WOFF_F2 1126400
#define WOFF_PS 1142784          // partial sums [4000][1024] bf16

// LDS strides (bf16 elems), %8==0 for 16B-aligned b128 rows
#define LSTR_H  392
#define LSTR_H2 136
#define LSTR_H3 264

static __device__ __forceinline__ floatx4 mfma16(bf16x8 a, bf16x8 b, floatx4 c) {
  return __builtin_amdgcn_mfma_f32_16x16x32_bf16(a, b, c, 0, 0, 0);
}

// ---------------------------------------------------------------------------
// One-launch weight repack. fp32 row-major [K][N] -> bf16 fragment order:
// dst[((nc*KT + kt)*CW + nl)*32 + kk] = src[(kt*32+kk)*N + nc*CW + nl]
// ---------------------------------------------------------------------------
static __device__ __forceinline__ void pack_one(const float* __restrict__ src,
                                                bf16* __restrict__ dst, int i,
                                                int K, int N, int CW) {
  int kk = i & 31;
  int t = i >> 5;
  int nl = t % CW;
  int t2 = t / CW;
  int KT = K >> 5;
  int kt = t2 % KT;
  int nc = t2 / KT;
  dst[i] = (bf16)src[(kt * 32 + kk) * N + nc * CW + nl];
}

__global__ void pack_all(const float* __restrict__ aw, const float* __restrict__ bw,
                         const float* __restrict__ p1w, const float* __restrict__ p2w,
                         const float* __restrict__ p3w, const float* __restrict__ f1w,
                         const float* __restrict__ f2w, bf16* __restrict__ wpk) {
  int i = blockIdx.x * 256 + threadIdx.x;   // grid sized exactly: WOFF_PS/256
  if (i < WOFF_BW)            pack_one(aw,  wpk + WOFF_AW, i - WOFF_AW,  64, 128, 128);
  else if (i < WOFF_P1)       pack_one(bw,  wpk + WOFF_BW, i - WOFF_BW,  32, 128, 128);
  else if (i < WOFF_P2)       pack_one(p1w, wpk + WOFF_P1, i - WOFF_P1, 384, 512, 128);
  else if (i < WOFF_P3)       pack_one(p2w, wpk + WOFF_P2, i - WOFF_P2, 512, 256, 128);
  else if (i < WOFF_F1)       pack_one(p3w, wpk + WOFF_P3, i - WOFF_P3, 256, 1024, 128);
  else if (i < WOFF_F2)       pack_one(f1w, wpk + WOFF_F1, i - WOFF_F1, 1024, 512, 128);
  else                        pack_one(f2w, wpk + WOFF_F2, i - WOFF_F2, 512, 32, 32);
}

// kstep, A from LDS (row-clamped), 2 B-frags from global: 4 A-reads, 8 MFMA
static __device__ __forceinline__ void kstep2(const bf16* __restrict__ Ab,
                                              int astride, int acol,
                                              const int* __restrict__ rm,
                                              const bf16* __restrict__ b0p,
                                              const bf16* __restrict__ b1p,
                                              floatx4* acc, int lq) {
  bf16x8 b0 = *(const bf16x8*)b0p;
  bf16x8 b1 = *(const bf16x8*)b1p;
#pragma unroll
  for (int mt = 0; mt < 4; ++mt) {
    bf16x8 a = *(const bf16x8*)(Ab + rm[mt] * astride + acol + lq * 8);
    acc[mt * 2]     = mfma16(a, b0, acc[mt * 2]);
    acc[mt * 2 + 1] = mfma16(a, b1, acc[mt * 2 + 1]);
  }
}

// kstep, A from LDS (row-clamped), 4 consecutive B-frags: 4 A-reads, 16 MFMA
static __device__ __forceinline__ void kstep4(const bf16* __restrict__ Ab,
                                              int astride, int acol,
                                              const int* __restrict__ rm,
                                              const bf16* __restrict__ bp,
                                              floatx4* acc, int lq) {
  bf16x8 bf[4];
#pragma unroll
  for (int j = 0; j < 4; ++j) bf[j] = *(const bf16x8*)(bp + j * 512);
#pragma unroll
  for (int mt = 0; mt < 4; ++mt) {
    bf16x8 a = *(const bf16x8*)(Ab + rm[mt] * astride + acol + lq * 8);
#pragma unroll
    for (int j = 0; j < 4; ++j)
      acc[mt * 4 + j] = mfma16(a, bf[j], acc[mt * 4 + j]);
  }
}

// ---------------------------------------------------------------------------
// seg_kernel: LDS = h[50x392] (39.2K) + h2chunk[50x136] (13.6K) = 52.8K;
// h3[50x264] overlays h. Pad rows (50..63) never stored: A-reads clamp the
// row index to 49 (duplicate data, excluded from the final masked sum).
// ---------------------------------------------------------------------------
__global__ __launch_bounds__(256, 2) void seg_kernel(
    const float* __restrict__ pairs, const float* __restrict__ ab,
    const float* __restrict__ bb, const float* __restrict__ p1b,
    const float* __restrict__ p2b, const bf16* __restrict__ wpk,
    bf16* __restrict__ psum) {
  __shared__ __align__(16) bf16 smem[26400];
  bf16* const hA = smem;          // h  [50 x 392]
  bf16* const hB = smem + 19600;  // h2 chunk [50 x 136]
  bf16* const h3 = smem;          // h3 [50 x 264], overlays hA (dead by then)

  const int tid = threadIdx.x;
  const int w = tid >> 6;
  const int lane = tid & 63;
  const int lm = lane & 15;
  const int lq = lane >> 4;
  const int blk = blockIdx.x;

  int rm[4];
#pragma unroll
  for (int mt = 0; mt < 4; ++mt) rm[mt] = min(mt * 16 + lm, 49);

  const float* const pb = pairs + (size_t)blk * 8000;  // 50 rows x 160

  const floatx4 fz = {0.f, 0.f, 0.f, 0.f};
  floatx4 acc[16];
  floatx4 acc3[16];

  // ---------------- embed: a1 / a2 / be -> hA[50,384] -------------------
#pragma unroll
  for (int sub = 0; sub < 3; ++sub) {
    const int acol = sub * 64;                 // pairs col base: 0 / 64 / 128
    const int nk = (sub == 2) ? 1 : 2;
    const bf16* wsrc = wpk + ((sub == 2) ? WOFF_BW : WOFF_AW);
    const float* bias = (sub == 2) ? bb : ab;
#pragma unroll
    for (int t = 0; t < 8; ++t) acc[t] = fz;
    for (int kt = 0; kt < nk; ++kt) {
      bf16x8 b0 = *(const bf16x8*)(wsrc + ((size_t)(kt * 128 + w * 16 + lm)) * 32 + lq * 8);
      bf16x8 b1 = *(const bf16x8*)(wsrc + ((size_t)(kt * 128 + (w + 4) * 16 + lm)) * 32 + lq * 8);
#pragma unroll
      for (int mt = 0; mt < 4; ++mt) {
        const float* pr = pb + rm[mt] * 160 + acol + kt * 32 + lq * 8;
        float4 u = *(const float4*)pr;
        float4 v = *(const float4*)(pr + 4);
        bf16x8 a = {(bf16)u.x, (bf16)u.y, (bf16)u.z, (bf16)u.w,
                    (bf16)v.x, (bf16)v.y, (bf16)v.z, (bf16)v.w};
        acc[mt * 2]     = mfma16(a, b0, acc[mt * 2]);
        acc[mt * 2 + 1] = mfma16(a, b1, acc[mt * 2 + 1]);
      }
    }
#pragma unroll
    for (int mt = 0; mt < 4; ++mt)
#pragma unroll
      for (int j = 0; j < 2; ++j) {
        int cl = (w + 4 * j) * 16 + lm;
        float bv = bias[cl];
        floatx4 c = acc[mt * 2 + j];
#pragma unroll
        for (int r = 0; r < 4; ++r) {
          int row = mt * 16 + lq * 4 + r;
          float vv = c[r] + bv;
          vv = vv > 0.f ? vv : 0.f;
          if (row < 50) hA[row * LSTR_H + sub * 128 + cl] = (bf16)vv;
        }
      }
  }
  __syncthreads();

  // ------- p1 (4 N-chunks of 128), each fused into p2 K-accumulation -------
#pragma unroll
  for (int t = 0; t < 16; ++t) acc3[t] = fz;

  for (int nc = 0; nc < 4; ++nc) {
#pragma unroll
    for (int t = 0; t < 8; ++t) acc[t] = fz;
#pragma unroll
    for (int kt = 0; kt < 12; ++kt)
      kstep2(hA, LSTR_H, kt * 32, rm,
             wpk + WOFF_P1 + ((size_t)((nc * 12 + kt) * 128 + w * 16 + lm)) * 32 + lq * 8,
             wpk + WOFF_P1 + ((size_t)((nc * 12 + kt) * 128 + (w + 4) * 16 + lm)) * 32 + lq * 8,
             acc, lq);
    __syncthreads();                      // prior p2 reads of hB done (WAR)
    // p1 epilogue -> hB (h2 chunk, stride 136)
#pragma unroll
    for (int mt = 0; mt < 4; ++mt)
#pragma unroll
      for (int j = 0; j < 2; ++j) {
        int cl = (w + 4 * j) * 16 + lm;
        float bv = p1b[nc * 128 + cl];
        floatx4 c = acc[mt * 2 + j];
#pragma unroll
        for (int r = 0; r < 4; ++r) {
          int row = mt * 16 + lq * 4 + r;
          float vv = c[r] + bv;
          vv = vv > 0.f ? vv : 0.f;
          if (row < 50) hB[row * LSTR_H2 + cl] = (bf16)vv;
        }
      }
    __syncthreads();                      // hB visible
#pragma unroll
    for (int kt2 = 0; kt2 < 4; ++kt2)
      kstep4(hB, LSTR_H2, kt2 * 32, rm,
             wpk + WOFF_P2 +
                 ((size_t)(((w >> 1) * 16 + nc * 4 + kt2) * 128 + (w & 1) * 64 + lm)) * 32 +
                 lq * 8,
             acc3, lq);
  }

  // p2 epilogue: h3 = relu(acc3 + p2b) -> h3 (overlays hA; disjoint from hB,
  // and all hA reads finished before the barriers inside the nc=3 iteration).
#pragma unroll
  for (int mt = 0; mt < 4; ++mt)
#pragma unroll
    for (int s = 0; s < 4; ++s) {
      int cl = w * 64 + s * 16 + lm;
      float bv = p2b[cl];
      floatx4 c = acc3[mt * 4 + s];
#pragma unroll
      for (int r = 0; r < 4; ++r) {
        int row = mt * 16 + lq * 4 + r;
        float vv = c[r] + bv;
        vv = vv > 0.f ? vv : 0.f;
        if (row < 50) h3[row * LSTR_H3 + cl] = (bf16)vv;
      }
    }
  __syncthreads();

  // ---------------- p3 (4 N-chunks of 256) + masked column sums ----------
  const int wn = w >> 1;
  const int wl = (w & 1) * 64;
  for (int c = 0; c < 4; ++c) {
#pragma unroll
    for (int t = 0; t < 16; ++t) acc[t] = fz;
#pragma unroll
    for (int kt = 0; kt < 8; ++kt)
      kstep4(h3, LSTR_H3, kt * 32, rm,
             wpk + WOFF_P3 + ((size_t)(((2 * c + wn) * 8 + kt) * 128 + wl + lm)) * 32 + lq * 8,
             acc, lq);
    // column sums over valid rows: mt<3 full; mt==3 rows 48,49 only (lq==0,
    // r=0,1). Clamped pad rows duplicate row 49 and are excluded here.
#pragma unroll
    for (int j = 0; j < 4; ++j) {
      float cs = 0.f;
#pragma unroll
      for (int mt = 0; mt < 4; ++mt) {
        floatx4 cc = acc[mt * 4 + j];
        float t4;
        if (mt < 3) t4 = cc[0] + cc[1] + cc[2] + cc[3];
        else        t4 = (lq == 0) ? (cc[0] + cc[1]) : 0.f;
        cs += t4;
      }
      cs += __shfl_xor(cs, 16, 64);
      cs += __shfl_xor(cs, 32, 64);
      if (lq == 0) {
        int col = c * 256 + w * 64 + j * 16 + lm;
        psum[(size_t)blk * 1024 + col] = (bf16)cs;
      }
    }
  }
}

// ---------------------------------------------------------------------------
// Head: per 16-row block, fuse combine (mean + p3 bias) then f1/f2/f3.
// ---------------------------------------------------------------------------
__global__ __launch_bounds__(256, 2) void head_kernel(
    const bf16* __restrict__ wpk, const bf16* __restrict__ psum,
    const int* __restrict__ idxp, const float* __restrict__ p3b,
    const float* __restrict__ f1b, const float* __restrict__ f2b,
    const float* __restrict__ f3w, const float* __restrict__ f3b,
    float* __restrict__ out) {
  __shared__ __align__(16) bf16 hp[16 * 1032];
  __shared__ __align__(16) bf16 h2[16 * 520];
  __shared__ __align__(16) bf16 h3s[16 * 40];

  const int tid = threadIdx.x;
  const int w = tid >> 6;
  const int lane = tid & 63;
  const int lm = lane & 15;
  const int lq = lane >> 4;
  const int r0 = blockIdx.x * 16;
  const bf16* wf1 = wpk + WOFF_F1;
  const floatx4 fz = {0.f, 0.f, 0.f, 0.f};

  // ---- combine: h_pair rows r0..r0+15 into LDS ----
  for (int i = tid; i < 16 * 1024; i += 256) {
    int row = i >> 10;
    int c = i & 1023;
    int seg = r0 + row;
    float s = (float)psum[(size_t)(2 * seg) * 1024 + c] +
              (float)psum[(size_t)(2 * seg + 1) * 1024 + c];
    hp[row * 1032 + c] = (bf16)(s / (float)idxp[seg] + p3b[c]);
  }
  __syncthreads();

  // ---- f1: [16,1024] @ [1024,128-per-wave] ----
  floatx4 a8[8];
#pragma unroll
  for (int t = 0; t < 8; ++t) a8[t] = fz;
#pragma unroll 4
  for (int kt = 0; kt < 32; ++kt) {
    bf16x8 a = *(const bf16x8*)(hp + lm * 1032 + kt * 32 + lq * 8);
#pragma unroll
    for (int nt = 0; nt < 8; ++nt) {
      bf16x8 b = *(const bf16x8*)(wf1 +
                    ((size_t)((w * 32 + kt) * 128 + nt * 16 + lm)) * 32 + lq * 8);
      a8[nt] = mfma16(a, b, a8[nt]);
    }
  }
#pragma unroll
  for (int nt = 0; nt < 8; ++nt) {
    int col = w * 128 + nt * 16 + lm;
    float bv = f1b[col];
    floatx4 c = a8[nt];
#pragma unroll
    for (int r = 0; r < 4; ++r) {
      float v = c[r] + bv;
      v = v > 0.f ? v : 0.f;
      h2[(lq * 4 + r) * 520 + col] = (bf16)v;
    }
  }
  __syncthreads();

  // ---- f2 + f3 on wave 0 ----
  if (w == 0) {
    floatx4 c2[2];
    c2[0] = fz; c2[1] = fz;
#pragma unroll
    for (int kt = 0; kt < 16; ++kt) {
      bf16x8 a = *(const bf16x8*)(h2 + lm * 520 + kt * 32 + lq * 8);
#pragma unroll
      for (int j = 0; j < 2; ++j) {
        bf16x8 b = *(const bf16x8*)(wpk + WOFF_F2 +
                      ((size_t)(kt * 32 + j * 16 + lm)) * 32 + lq * 8);
        c2[j] = mfma16(a, b, c2[j]);
      }
    }
#pragma unroll
    for (int j = 0; j < 2; ++j) {
      int col = j * 16 + lm;
      float bv = f2b[col];
#pragma unroll
      for (int r = 0; r < 4; ++r) {
        float v = c2[j][r] + bv;
        v = v > 0.f ? v : 0.f;
        h3s[(lq * 4 + r) * 40 + col] = (bf16)v;
      }
    }
    float ps = 0.f;
#pragma unroll
    for (int jj = 0; jj < 8; ++jj)
      ps += (float)h3s[lm * 40 + lq * 8 + jj] * f3w[lq * 8 + jj];
    ps += __shfl_xor(ps, 16, 64);
    ps += __shfl_xor(ps, 32, 64);
    if (lq == 0) out[r0 + lm] = ps + f3b[0];
  }
}

// ---------------------------------------------------------------------------
extern "C" void kernel_launch(void* const* d_in, const int* in_sizes, int n_in,
                              void* d_out, int out_size, void* d_ws,
                              size_t ws_size, hipStream_t stream) {
  (void)in_sizes; (void)n_in; (void)out_size; (void)ws_size;
  const float* pairs = (const float*)d_in[0];
  const int*   idxp  = (const int*)d_in[1];
  // d_in[2] = ref_feats (unused by the reference)
  const float* aw  = (const float*)d_in[3];
  const float* ab  = (const float*)d_in[4];
  const float* bw  = (const float*)d_in[5];
  const float* bb  = (const float*)d_in[6];
  const float* p1w = (const float*)d_in[7];
  const float* p1b = (const float*)d_in[8];
  const float* p2w = (const float*)d_in[9];
  const float* p2b = (const float*)d_in[10];
  const float* p3w = (const float*)d_in[11];
  const float* p3b = (const float*)d_in[12];
  const float* f1w = (const float*)d_in[13];
  const float* f1b = (const float*)d_in[14];
  const float* f2w = (const float*)d_in[15];
  const float* f2b = (const float*)d_in[16];
  const float* f3w = (const float*)d_in[17];
  const float* f3b = (const float*)d_in[18];

  bf16* wpk = (bf16*)d_ws;

  pack_all<<<WOFF_PS / 256, 256, 0, stream>>>(aw, bw, p1w, p2w, p3w, f1w, f2w,
                                              wpk);
  seg_kernel<<<4000, 256, 0, stream>>>(pairs, ab, bb, p1b, p2b, wpk,
                                       wpk + WOFF_PS);
  head_kernel<<<125, 256, 0, stream>>>(wpk, wpk + WOFF_PS, idxp, p3b, f1b, f2b,
                                       f3w, f3b, (float*)d_out);
}